// Round 1
// baseline (508.543 us; speedup 1.0000x reference)
//
#include <hip/hip_runtime.h>

// TensorProduct: 128x0e+128x1o (x1) ⊗ 1x0e+1x1o (x2) -> 128x0e+128x1o, 'uvw' weights.
//
// Folded single-GEMM formulation (scalars b into A-rows, norms into weights):
//   out0[z,w]   = [b0*a0 ; a1·b1]   @ V0,  V0 = [W0/16 ; W3/(16*sqrt3)]  (256x128)
//   out1[z,w,k] = [b1k*a0 ; b0*a1k] @ V1,  V1 = [W1/16 ; W2/16]          (256x128)
// Memory floor ~65us (411MB @ 6.3TB/s). Baseline hit 143us/dispatch at 36% BW:
// latency-serialized (loads waited inside the barrier-to-barrier chain) + 22%
// write amplification from stride-3 out1 dword scatter.
//
// This version:
//  * Depth-1 register prefetch, 2x-unrolled loop with alternating P/N reg sets
//    (no copy -> no early vmcnt wait; P and N never simultaneously live, so the
//    128-reg/wave budget (Bf=64 AGPR + ~60 VGPR) that gives 2 blocks/CU holds).
//    Loads are issued AFTER the 2nd __syncthreads (syncthreads drains vmcnt(0)),
//    so they stay in flight across MFMA+stores and are drained at the next
//    iteration's first barrier -- by which point latency is covered.
//  * zt-major out1 epilogue: k3 triplet accumulators live together, stored as
//    12B/lane (dwordx3) -> lanes byte-contiguous, full-line writes, no RMW.
//  * out0 stores nontemporal (full-line by construction; output never re-read;
//    keeps L2/L3 for the streamed inputs).
//  * native (__bf16) casts -> v_cvt_pk_bf16_f32 (RNE, same numerics) instead of
//    4-op manual round: ~3x less stage-phase VALU.
//
// C/D layout (m89-verified): col = lane&15 (=n), row = (lane>>4)*4 + reg (=m).

#define Z_TOTAL   100000
#define BM        32
#define NTILES_Z  (Z_TOTAL / BM)   // 3125, exact
#define GRID      512
#define THREADS   512

using bf16x8 = __attribute__((ext_vector_type(8))) __bf16;
using f32x4  = __attribute__((ext_vector_type(4))) float;

struct __align__(4) F3 { float x, y, z; };   // 12B -> global_store_dwordx3

struct TileRegs {
    float4 b;          // x2 row: b0, b1x, b1y, b1z
    float4 a0a, a0b;   // 8 floats of a0 chunk
    float4 a1[6];      // 24 floats of a1 chunk (u,3 interleaved)
};

// LDS: 128 rows x 256 bf16 (512B rows). chunk = 16B unit index (0..31).
// XOR-swizzle low 3 bits of chunk by (row&7): conflict-floor for writes+reads.
__device__ __forceinline__ int lds_idx(int row, int chunk) {
    return row * 256 + ((chunk ^ (row & 7)) << 3);
}

__device__ __forceinline__ void tile_load(TileRegs& T, const float* __restrict__ x1,
                                          const float* __restrict__ x2,
                                          int z0, int zl, int u0) {
    const float* xr = x1 + (size_t)(z0 + zl) * 512;
    T.b   = *(const float4*)(x2 + (size_t)(z0 + zl) * 4);
    T.a0a = *(const float4*)(xr + u0);
    T.a0b = *(const float4*)(xr + u0 + 4);
    #pragma unroll
    for (int i = 0; i < 6; ++i)
        T.a1[i] = *(const float4*)(xr + 128 + u0 * 3 + i * 4);
}

__device__ __forceinline__ void tile_stage(const TileRegs& T, unsigned short* lds,
                                           int zl, int ug) {
    const float b0 = T.b.x, b1x = T.b.y, b1y = T.b.z, b1z = T.b.w;
    const float a0[8] = {T.a0a.x, T.a0a.y, T.a0a.z, T.a0a.w,
                         T.a0b.x, T.a0b.y, T.a0b.z, T.a0b.w};
    bf16x8 pk;
    #pragma unroll
    for (int i = 0; i < 8; ++i) pk[i] = (__bf16)(b0 * a0[i]);
    *(bf16x8*)&lds[lds_idx(zl, ug)] = pk;              // R0 lo: b0*a0
    #pragma unroll
    for (int i = 0; i < 8; ++i) pk[i] = (__bf16)(b1x * a0[i]);
    *(bf16x8*)&lds[lds_idx(32 + zl, ug)] = pk;         // R1x lo
    #pragma unroll
    for (int i = 0; i < 8; ++i) pk[i] = (__bf16)(b1y * a0[i]);
    *(bf16x8*)&lds[lds_idx(64 + zl, ug)] = pk;         // R1y lo
    #pragma unroll
    for (int i = 0; i < 8; ++i) pk[i] = (__bf16)(b1z * a0[i]);
    *(bf16x8*)&lds[lds_idx(96 + zl, ug)] = pk;         // R1z lo

    float a1[24];
    #pragma unroll
    for (int i = 0; i < 6; ++i) {
        a1[i*4+0] = T.a1[i].x; a1[i*4+1] = T.a1[i].y;
        a1[i*4+2] = T.a1[i].z; a1[i*4+3] = T.a1[i].w;
    }
    #pragma unroll
    for (int i = 0; i < 8; ++i)                        // R0 hi: a1·b1 (1/sqrt3 in V0)
        pk[i] = (__bf16)(a1[3*i]*b1x + a1[3*i+1]*b1y + a1[3*i+2]*b1z);
    *(bf16x8*)&lds[lds_idx(zl, 16 + ug)] = pk;
    #pragma unroll
    for (int i = 0; i < 8; ++i) pk[i] = (__bf16)(b0 * a1[3*i + 0]);
    *(bf16x8*)&lds[lds_idx(32 + zl, 16 + ug)] = pk;    // R1x hi: b0*a1x
    #pragma unroll
    for (int i = 0; i < 8; ++i) pk[i] = (__bf16)(b0 * a1[3*i + 1]);
    *(bf16x8*)&lds[lds_idx(64 + zl, 16 + ug)] = pk;    // R1y hi
    #pragma unroll
    for (int i = 0; i < 8; ++i) pk[i] = (__bf16)(b0 * a1[3*i + 2]);
    *(bf16x8*)&lds[lds_idx(96 + zl, 16 + ug)] = pk;    // R1z hi
}

__device__ __forceinline__ void mfma_store(const unsigned short* lds,
                                           const bf16x8 Bf[2][8],
                                           float* __restrict__ out,
                                           int z0, int m16, int q, int n) {
    // out0: rows 0..31 of A, weights V0. Full-line stores -> nontemporal.
    #pragma unroll
    for (int m2 = 0; m2 < 2; ++m2) {
        f32x4 acc = {0.f, 0.f, 0.f, 0.f};
        const int r = m2 * 16 + m16;
        #pragma unroll
        for (int kt = 0; kt < 8; ++kt) {
            const bf16x8 a = *(const bf16x8*)&lds[lds_idx(r, kt * 4 + q)];
            acc = __builtin_amdgcn_mfma_f32_16x16x32_bf16(a, Bf[0][kt], acc, 0, 0, 0);
        }
        #pragma unroll
        for (int reg = 0; reg < 4; ++reg) {
            const int z = z0 + m2 * 16 + q * 4 + reg;
            __builtin_nontemporal_store(acc[reg], out + (size_t)z * 512 + n);
        }
    }
    // out1: zt-major so the k3 triplet is live together -> packed 12B stores
    // (lane m16 writes bytes [12*m16, 12*m16+12) of the wave's 192B span:
    //  byte-contiguous, 64B-line-aligned per wave -> no partial-line RMW).
    #pragma unroll
    for (int zt = 0; zt < 2; ++zt) {
        f32x4 a3[3];
        #pragma unroll
        for (int k3 = 0; k3 < 3; ++k3) {
            a3[k3] = (f32x4){0.f, 0.f, 0.f, 0.f};
            const int r = 32 + k3 * 32 + zt * 16 + m16;
            #pragma unroll
            for (int kt = 0; kt < 8; ++kt) {
                const bf16x8 a = *(const bf16x8*)&lds[lds_idx(r, kt * 4 + q)];
                a3[k3] = __builtin_amdgcn_mfma_f32_16x16x32_bf16(a, Bf[1][kt], a3[k3], 0, 0, 0);
            }
        }
        #pragma unroll
        for (int reg = 0; reg < 4; ++reg) {
            const int z = z0 + zt * 16 + q * 4 + reg;
            F3 v; v.x = a3[0][reg]; v.y = a3[1][reg]; v.z = a3[2][reg];
            *(F3*)(out + (size_t)z * 512 + 128 + n * 3) = v;
        }
    }
}

__global__ __launch_bounds__(THREADS, 4)
void tp_kernel(const float* __restrict__ x1, const float* __restrict__ x2,
               const float* __restrict__ wts, float* __restrict__ out)
{
    __shared__ __align__(16) unsigned short lds[128 * 256];   // 64 KB

    const int t    = threadIdx.x;
    const int lane = t & 63;
    const int wv   = t >> 6;        // wave id 0..7 == n-tile
    const int m16  = lane & 15;
    const int q    = lane >> 4;

    // ---- persistent B fragments (weights), 64 regs/lane (AGPR-resident) ----
    const float S16 = 0.0625f;                                // 1/16
    const float S48 = 0.0625f * 0.57735026918962576f;         // 1/(16*sqrt(3))
    bf16x8 Bf[2][8];
    {
        const int n = wv * 16 + m16;
        #pragma unroll
        for (int mat = 0; mat < 2; ++mat) {
            #pragma unroll
            for (int kt = 0; kt < 8; ++kt) {
                bf16x8 bb;
                #pragma unroll
                for (int j = 0; j < 8; ++j) {
                    const int k = kt * 32 + q * 8 + j;
                    float v;
                    if (mat == 0) {  // V0 = [W0/16 ; W3/(16*sqrt3)]
                        v = (k < 128) ? wts[k * 128 + n] * S16
                                      : wts[49152 + (k - 128) * 128 + n] * S48;
                    } else {         // V1 = [W1/16 ; W2/16]
                        v = (k < 128) ? wts[16384 + k * 128 + n] * S16
                                      : wts[32768 + (k - 128) * 128 + n] * S16;
                    }
                    bb[j] = (__bf16)v;
                }
                Bf[mat][kt] = bb;
            }
        }
    }

    const int zl = t >> 4;          // local z row 0..31
    const int ug = t & 15;          // u-group (8 u's per thread)
    const int u0 = ug * 8;
    const int n  = wv * 16 + m16;

    // ---- software pipeline: 2x-unrolled, alternating P/N register tiles ----
    int tile = blockIdx.x;          // GRID=512 < NTILES_Z: every block has >=1 tile
    TileRegs P, N;
    tile_load(P, x1, x2, tile * BM, zl, u0);

    for (;;) {
        int nx = tile + GRID;
        __syncthreads();                 // LDS reuse guard; drains prev prefetch
        tile_stage(P, lds, zl, ug);
        __syncthreads();
        if (nx < NTILES_Z)               // issue AFTER barrier: stays in flight
            tile_load(N, x1, x2, nx * BM, zl, u0);
        mfma_store(lds, Bf, out, tile * BM, m16, q, n);
        if (nx >= NTILES_Z) return;
        tile = nx;

        nx = tile + GRID;
        __syncthreads();
        tile_stage(N, lds, zl, ug);
        __syncthreads();
        if (nx < NTILES_Z)
            tile_load(P, x1, x2, nx * BM, zl, u0);
        mfma_store(lds, Bf, out, tile * BM, m16, q, n);
        if (nx >= NTILES_Z) return;
        tile = nx;
    }
}

extern "C" void kernel_launch(void* const* d_in, const int* in_sizes, int n_in,
                              void* d_out, int out_size, void* d_ws, size_t ws_size,
                              hipStream_t stream) {
    (void)in_sizes; (void)n_in; (void)d_ws; (void)ws_size; (void)out_size;
    const float* x1  = (const float*)d_in[0];
    const float* x2  = (const float*)d_in[1];
    const float* wts = (const float*)d_in[2];
    float* out = (float*)d_out;
    tp_kernel<<<dim3(GRID), dim3(THREADS), 0, stream>>>(x1, x2, wts, out);
}

// Round 2
// 353.214 us; speedup vs baseline: 1.4398x; 1.4398x over previous
//
#include <hip/hip_runtime.h>

// TensorProduct: 128x0e+128x1o (x1) ⊗ 1x0e+1x1o (x2) -> 128x0e+128x1o, 'uvw' weights.
//
// Folded single-GEMM formulation (scalars b into A-rows, norms into weights):
//   out0[z,w]   = [b0*a0 ; a1·b1]   @ V0,  V0 = [W0/16 ; W3/(16*sqrt3)]  (256x128)
//   out1[z,w,k] = [b1k*a0 ; b0*a1k] @ V1,  V1 = [W1/16 ; W2/16]          (256x128)
// Memory floor ~65us (411MB @ 6.3TB/s).
//
// History: r0 (no pipeline, 2 blk/CU) = 143us/dispatch @36% BW, latency-serialized.
// r1 added depth-1 register prefetch under __launch_bounds__(512,4): budget
// 128 regs/wave; Bf(64) + P/N TileRegs(72) overflowed -> scratch spill; FETCH
// +237GB / WRITE +265GB of spill traffic, 283us. VGPR_Count stayed 64 = tell.
//
// r2 (this): SAME pipeline, but 1 block/CU: __launch_bounds__(512,2) doubles
// the register budget to 256/wave (Bf 64 + P/N 72 + working ~40 fits, no
// spill), GRID=256 (persistent, 1 resident block/CU; LDS 64KB allowed only 2
// anyway). TLP lost to the pipeline's ILP: per tile ~137KB (loads t+1 +
// stores t) sits in the vmcnt queue and drains at full per-CU BW share during
// the barrier wait, so memory streams ~90% of the time even with one block.
// Nontemporal out0 stores reverted (confounded in r1; plain write-back).
// Packed 12B/lane out1 stores kept (full-line writes, no RMW).
//
// C/D layout (m89-verified): col = lane&15 (=n), row = (lane>>4)*4 + reg (=m).

#define Z_TOTAL   100000
#define BM        32
#define NTILES_Z  (Z_TOTAL / BM)   // 3125, exact
#define GRID      256
#define THREADS   512

using bf16x8 = __attribute__((ext_vector_type(8))) __bf16;
using f32x4  = __attribute__((ext_vector_type(4))) float;

struct __align__(4) F3 { float x, y, z; };   // 12B packed out1 store

struct TileRegs {
    float4 b;          // x2 row: b0, b1x, b1y, b1z
    float4 a0a, a0b;   // 8 floats of a0 chunk
    float4 a1[6];      // 24 floats of a1 chunk (u,3 interleaved)
};

// LDS: 128 rows x 256 bf16 (512B rows). chunk = 16B unit index (0..31).
// XOR-swizzle low 3 bits of chunk by (row&7): conflict-floor for writes+reads.
__device__ __forceinline__ int lds_idx(int row, int chunk) {
    return row * 256 + ((chunk ^ (row & 7)) << 3);
}

__device__ __forceinline__ void tile_load(TileRegs& T, const float* __restrict__ x1,
                                          const float* __restrict__ x2,
                                          int z0, int zl, int u0) {
    const float* xr = x1 + (size_t)(z0 + zl) * 512;
    T.b   = *(const float4*)(x2 + (size_t)(z0 + zl) * 4);
    T.a0a = *(const float4*)(xr + u0);
    T.a0b = *(const float4*)(xr + u0 + 4);
    #pragma unroll
    for (int i = 0; i < 6; ++i)
        T.a1[i] = *(const float4*)(xr + 128 + u0 * 3 + i * 4);
}

__device__ __forceinline__ void tile_stage(const TileRegs& T, unsigned short* lds,
                                           int zl, int ug) {
    const float b0 = T.b.x, b1x = T.b.y, b1y = T.b.z, b1z = T.b.w;
    const float a0[8] = {T.a0a.x, T.a0a.y, T.a0a.z, T.a0a.w,
                         T.a0b.x, T.a0b.y, T.a0b.z, T.a0b.w};
    bf16x8 pk;
    #pragma unroll
    for (int i = 0; i < 8; ++i) pk[i] = (__bf16)(b0 * a0[i]);
    *(bf16x8*)&lds[lds_idx(zl, ug)] = pk;              // R0 lo: b0*a0
    #pragma unroll
    for (int i = 0; i < 8; ++i) pk[i] = (__bf16)(b1x * a0[i]);
    *(bf16x8*)&lds[lds_idx(32 + zl, ug)] = pk;         // R1x lo
    #pragma unroll
    for (int i = 0; i < 8; ++i) pk[i] = (__bf16)(b1y * a0[i]);
    *(bf16x8*)&lds[lds_idx(64 + zl, ug)] = pk;         // R1y lo
    #pragma unroll
    for (int i = 0; i < 8; ++i) pk[i] = (__bf16)(b1z * a0[i]);
    *(bf16x8*)&lds[lds_idx(96 + zl, ug)] = pk;         // R1z lo

    float a1[24];
    #pragma unroll
    for (int i = 0; i < 6; ++i) {
        a1[i*4+0] = T.a1[i].x; a1[i*4+1] = T.a1[i].y;
        a1[i*4+2] = T.a1[i].z; a1[i*4+3] = T.a1[i].w;
    }
    #pragma unroll
    for (int i = 0; i < 8; ++i)                        // R0 hi: a1·b1 (1/sqrt3 in V0)
        pk[i] = (__bf16)(a1[3*i]*b1x + a1[3*i+1]*b1y + a1[3*i+2]*b1z);
    *(bf16x8*)&lds[lds_idx(zl, 16 + ug)] = pk;
    #pragma unroll
    for (int i = 0; i < 8; ++i) pk[i] = (__bf16)(b0 * a1[3*i + 0]);
    *(bf16x8*)&lds[lds_idx(32 + zl, 16 + ug)] = pk;    // R1x hi: b0*a1x
    #pragma unroll
    for (int i = 0; i < 8; ++i) pk[i] = (__bf16)(b0 * a1[3*i + 1]);
    *(bf16x8*)&lds[lds_idx(64 + zl, 16 + ug)] = pk;    // R1y hi
    #pragma unroll
    for (int i = 0; i < 8; ++i) pk[i] = (__bf16)(b0 * a1[3*i + 2]);
    *(bf16x8*)&lds[lds_idx(96 + zl, 16 + ug)] = pk;    // R1z hi
}

__device__ __forceinline__ void mfma_store(const unsigned short* lds,
                                           const bf16x8 Bf[2][8],
                                           float* __restrict__ out,
                                           int z0, int m16, int q, int n) {
    // out0: rows 0..31 of A, weights V0. 16 consecutive lanes write 64B
    // line-aligned -> full-line writes already.
    #pragma unroll
    for (int m2 = 0; m2 < 2; ++m2) {
        f32x4 acc = {0.f, 0.f, 0.f, 0.f};
        const int r = m2 * 16 + m16;
        #pragma unroll
        for (int kt = 0; kt < 8; ++kt) {
            const bf16x8 a = *(const bf16x8*)&lds[lds_idx(r, kt * 4 + q)];
            acc = __builtin_amdgcn_mfma_f32_16x16x32_bf16(a, Bf[0][kt], acc, 0, 0, 0);
        }
        #pragma unroll
        for (int reg = 0; reg < 4; ++reg) {
            const int z = z0 + m2 * 16 + q * 4 + reg;
            out[(size_t)z * 512 + n] = acc[reg];
        }
    }
    // out1: zt-major so the k3 triplet is live together -> packed 12B stores
    // (lane m16 writes bytes [12*m16, 12*m16+12) of the wave's 192B span:
    //  byte-contiguous, 64B-line-aligned per wave -> no partial-line RMW).
    #pragma unroll
    for (int zt = 0; zt < 2; ++zt) {
        f32x4 a3[3];
        #pragma unroll
        for (int k3 = 0; k3 < 3; ++k3) {
            a3[k3] = (f32x4){0.f, 0.f, 0.f, 0.f};
            const int r = 32 + k3 * 32 + zt * 16 + m16;
            #pragma unroll
            for (int kt = 0; kt < 8; ++kt) {
                const bf16x8 a = *(const bf16x8*)&lds[lds_idx(r, kt * 4 + q)];
                a3[k3] = __builtin_amdgcn_mfma_f32_16x16x32_bf16(a, Bf[1][kt], a3[k3], 0, 0, 0);
            }
        }
        #pragma unroll
        for (int reg = 0; reg < 4; ++reg) {
            const int z = z0 + zt * 16 + q * 4 + reg;
            F3 v; v.x = a3[0][reg]; v.y = a3[1][reg]; v.z = a3[2][reg];
            *(F3*)(out + (size_t)z * 512 + 128 + n * 3) = v;
        }
    }
}

__global__ __launch_bounds__(THREADS, 2)   // 2 waves/SIMD -> 256 regs/wave: P/N+Bf fit
void tp_kernel(const float* __restrict__ x1, const float* __restrict__ x2,
               const float* __restrict__ wts, float* __restrict__ out)
{
    __shared__ __align__(16) unsigned short lds[128 * 256];   // 64 KB

    const int t    = threadIdx.x;
    const int lane = t & 63;
    const int wv   = t >> 6;        // wave id 0..7 == n-tile
    const int m16  = lane & 15;
    const int q    = lane >> 4;

    // ---- persistent B fragments (weights), 64 regs/lane ----
    const float S16 = 0.0625f;                                // 1/16
    const float S48 = 0.0625f * 0.57735026918962576f;         // 1/(16*sqrt(3))
    bf16x8 Bf[2][8];
    {
        const int n = wv * 16 + m16;
        #pragma unroll
        for (int mat = 0; mat < 2; ++mat) {
            #pragma unroll
            for (int kt = 0; kt < 8; ++kt) {
                bf16x8 bb;
                #pragma unroll
                for (int j = 0; j < 8; ++j) {
                    const int k = kt * 32 + q * 8 + j;
                    float v;
                    if (mat == 0) {  // V0 = [W0/16 ; W3/(16*sqrt3)]
                        v = (k < 128) ? wts[k * 128 + n] * S16
                                      : wts[49152 + (k - 128) * 128 + n] * S48;
                    } else {         // V1 = [W1/16 ; W2/16]
                        v = (k < 128) ? wts[16384 + k * 128 + n] * S16
                                      : wts[32768 + (k - 128) * 128 + n] * S16;
                    }
                    bb[j] = (__bf16)v;
                }
                Bf[mat][kt] = bb;
            }
        }
    }

    const int zl = t >> 4;          // local z row 0..31
    const int ug = t & 15;          // u-group (8 u's per thread)
    const int u0 = ug * 8;
    const int n  = wv * 16 + m16;

    // ---- software pipeline: 2x-unrolled, alternating P/N register tiles ----
    int tile = blockIdx.x;          // GRID=256 < NTILES_Z: every block has >=1 tile
    TileRegs P, N;
    tile_load(P, x1, x2, tile * BM, zl, u0);

    for (;;) {
        int nx = tile + GRID;
        __syncthreads();                 // LDS reuse guard; drains prev prefetch
        tile_stage(P, lds, zl, ug);
        __syncthreads();
        if (nx < NTILES_Z)               // issue AFTER barrier: stays in flight
            tile_load(N, x1, x2, nx * BM, zl, u0);
        mfma_store(lds, Bf, out, tile * BM, m16, q, n);
        if (nx >= NTILES_Z) return;
        tile = nx;

        nx = tile + GRID;
        __syncthreads();
        tile_stage(N, lds, zl, ug);
        __syncthreads();
        if (nx < NTILES_Z)
            tile_load(P, x1, x2, nx * BM, zl, u0);
        mfma_store(lds, Bf, out, tile * BM, m16, q, n);
        if (nx >= NTILES_Z) return;
        tile = nx;
    }
}

extern "C" void kernel_launch(void* const* d_in, const int* in_sizes, int n_in,
                              void* d_out, int out_size, void* d_ws, size_t ws_size,
                              hipStream_t stream) {
    (void)in_sizes; (void)n_in; (void)d_ws; (void)ws_size; (void)out_size;
    const float* x1  = (const float*)d_in[0];
    const float* x2  = (const float*)d_in[1];
    const float* wts = (const float*)d_in[2];
    float* out = (float*)d_out;
    tp_kernel<<<dim3(GRID), dim3(THREADS), 0, stream>>>(x1, x2, wts, out);
}